// Round 10
// baseline (270.533 us; speedup 1.0000x reference)
//
#include <hip/hip_runtime.h>
#include <stdint.h>

#define T_LEN 1024
#define NSTATE 32

typedef int v2i __attribute__((ext_vector_type(2)));

__device__ __forceinline__ float max3f(float a, float b, float c) {
    return fmaxf(fmaxf(a, b), c);   // v_max3_f32
}
__device__ __forceinline__ int min3i(int a, int b, int c) {
    return min(min(a, b), c);       // v_min3_i32
}

__launch_bounds__(64)
__global__ void viterbi_kernel(const float* __restrict__ logits,
                               const float* __restrict__ trans,
                               const int* __restrict__ seqlen,
                               int* __restrict__ out)
{
    const int lane = threadIdx.x;   // 0..63
    const int half = lane >> 5;     // candidate half this lane reduces
    const int j    = lane & 31;     // output column (lanes j, j+32 duplicate)
    const int h16  = half * 16;

    __shared__ __align__(16) float st[NSTATE];   // state vector (broadcast row)
    __shared__ uint8_t bp[T_LEN * NSTATE];       // backptrs, t=1..L-1
    __shared__ uint8_t Farr[NSTATE * NSTATE];    // chunk functions
    __shared__ uint8_t earr[NSTATE];             // chunk entry tags
    __shared__ __align__(16) int pred[T_LEN];    // output row

    int L = seqlen[blockIdx.x];
    L = min(max(L, 0), T_LEN);

    // transition column j, rows h16..h16+15 (registers, loaded once)
    float tr[16];
#pragma unroll
    for (int k = 0; k < 16; ++k)
        tr[k] = trans[(h16 + k) * NSTATE + j];

    const float* lg = logits + (size_t)blockIdx.x * T_LEN * NSTATE;

    // running value of column j (dup in lanes j, j+32)
    float ns = lg[j];

    // init state row + first broadcast reads (constant addresses)
    st[j] = ns;
    const float4* stv = reinterpret_cast<const float4*>(st) + half * 4;
    float4 q0 = stv[0], q1 = stv[1], q2 = stv[2], q3 = stv[3];

    // CHAIN(t): the serially-dependent part. Consumes q*=S_{t-1}, produces
    // S_t (ns, st row, reloaded q*) and exports v[16], gm for deferred argmax.
    auto chain = [&](float lgt, bool act, float (&vo)[16], float& gmo) {
        vo[0]=q0.x+tr[0];  vo[1]=q0.y+tr[1];  vo[2]=q0.z+tr[2];  vo[3]=q0.w+tr[3];
        vo[4]=q1.x+tr[4];  vo[5]=q1.y+tr[5];  vo[6]=q1.z+tr[6];  vo[7]=q1.w+tr[7];
        vo[8]=q2.x+tr[8];  vo[9]=q2.y+tr[9];  vo[10]=q2.z+tr[10];vo[11]=q2.w+tr[11];
        vo[12]=q3.x+tr[12];vo[13]=q3.y+tr[13];vo[14]=q3.z+tr[14];vo[15]=q3.w+tr[15];

        float a0 = max3f(vo[0],  vo[1],  vo[2]);
        float a1 = max3f(vo[3],  vo[4],  vo[5]);
        float a2 = max3f(vo[6],  vo[7],  vo[8]);
        float a3 = max3f(vo[9],  vo[10], vo[11]);
        float a4 = max3f(vo[12], vo[13], vo[14]);
        float b0 = max3f(a0, a1, a2);
        float b1 = max3f(a3, a4, vo[15]);
        float hm = fmaxf(b0, b1);

        v2i sw = __builtin_amdgcn_permlane32_swap(__float_as_int(hm),
                                                  __float_as_int(hm), false, false);
        float gm = fmaxf(hm, fmaxf(__int_as_float(sw[0]), __int_as_float(sw[1])));
        gmo = gm;

        float nsn = gm + lgt;          // same single-rounding add order as ref
        ns = act ? nsn : ns;           // uniform predication (padded steps freeze)

        st[j] = ns;                    // publish S_t
        q0 = stv[0]; q1 = stv[1]; q2 = stv[2]; q3 = stv[3];   // reload for t+1
    };

    // AMAX(t): deferred argmax of a PREVIOUS step — independent of the current
    // chain, giving the scheduler filler for chain stall cycles.
    auto amax = [&](int t, const float (&vi)[16], float gmi) {
        int ix[16];
#pragma unroll
        for (int k = 0; k < 16; ++k)
            ix[k] = (vi[k] == gmi) ? (h16 + k) : 64;
        int c0 = min3i(ix[0],  ix[1],  ix[2]);
        int c1 = min3i(ix[3],  ix[4],  ix[5]);
        int c2 = min3i(ix[6],  ix[7],  ix[8]);
        int c3 = min3i(ix[9],  ix[10], ix[11]);
        int c4 = min3i(ix[12], ix[13], ix[14]);
        int d0 = min3i(c0, c1, c2);
        int d1 = min3i(c3, c4, ix[15]);
        int ih = min(d0, d1);
        v2i swi = __builtin_amdgcn_permlane32_swap(ih, ih, false, false);
        int idx = min3i(ih, swi[0], swi[1]);

        // padded steps clamp to row 1023 (never read: L-1 <= 1022)
        bp[min(t, 1023) * NSTATE + j] = (uint8_t)idx;
    };

    // ---------------- forward: 1-deep software pipeline ----------------
    if (L >= 2) {
        float vX[16], vY[16];   // even-t bank / odd-t bank (static indexing)
        float gmX, gmY;

        float lg1 = lg[NSTATE + j];
        chain(lg1, true, vY, gmY);              // t=1 (odd -> Y)

        float pre[8];
#pragma unroll
        for (int u = 0; u < 8; ++u)
            pre[u] = lg[min(2 + u, 1023) * NSTATE + j];

        const int m = L - 2;                    // steps t=2..L-1
        const int M = (m + 7) & ~7;             // padded to x8

        for (int t = 2; t < 2 + M; t += 8) {
            chain(pre[0], (t+0) < L, vX, gmX); amax(t-1, vY, gmY);
            pre[0] = lg[min(t+8,  1023) * NSTATE + j];
            chain(pre[1], (t+1) < L, vY, gmY); amax(t+0, vX, gmX);
            pre[1] = lg[min(t+9,  1023) * NSTATE + j];
            chain(pre[2], (t+2) < L, vX, gmX); amax(t+1, vY, gmY);
            pre[2] = lg[min(t+10, 1023) * NSTATE + j];
            chain(pre[3], (t+3) < L, vY, gmY); amax(t+2, vX, gmX);
            pre[3] = lg[min(t+11, 1023) * NSTATE + j];
            chain(pre[4], (t+4) < L, vX, gmX); amax(t+3, vY, gmY);
            pre[4] = lg[min(t+12, 1023) * NSTATE + j];
            chain(pre[5], (t+5) < L, vY, gmY); amax(t+4, vX, gmX);
            pre[5] = lg[min(t+13, 1023) * NSTATE + j];
            chain(pre[6], (t+6) < L, vX, gmX); amax(t+5, vY, gmY);
            pre[6] = lg[min(t+14, 1023) * NSTATE + j];
            chain(pre[7], (t+7) < L, vY, gmY); amax(t+6, vX, gmX);
            pre[7] = lg[min(t+15, 1023) * NSTATE + j];
        }
        amax(1 + M, vY, gmY);                   // last chain step (1+M odd -> Y)
    }

    // ---------------- last_tag = argmax(final state) ----------------
    float m2 = ns;
#pragma unroll
    for (int d = 1; d < 64; d <<= 1) m2 = fmaxf(m2, __shfl_xor(m2, d));
    int ii = (ns == m2) ? j : 64;
#pragma unroll
    for (int d = 1; d < 64; d <<= 1) ii = min(ii, __shfl_xor(ii, d));
    const int ft = ii;   // last tag (identical in all lanes)

    __syncthreads();   // bp visible for backtrace

    // ---- phase 1: chunk functions, all 32 start states (halves split k) ----
    {
        const int c = lane & 31;
        const int j0base = (lane >> 5) * 16;
        int tags[16];
#pragma unroll
        for (int k = 0; k < 16; ++k) tags[k] = j0base + k;
        const int thi = c * 32 + 31;
        for (int s = 0; s < 32; ++s) {
            int t = thi - s;
            bool valid = (t >= 1) && (t <= L - 1);
            int tc = min(max(t, 1), max(L - 1, 1));
            int base = tc * NSTATE;
#pragma unroll
            for (int k = 0; k < 16; ++k) {
                int nt = bp[base + tags[k]];
                tags[k] = valid ? nt : tags[k];
            }
        }
#pragma unroll
        for (int k = 0; k < 16; ++k)
            Farr[c * 32 + j0base + k] = (uint8_t)tags[k];
    }
    __syncthreads();

    // ---- phase 2: compose chunk entries (serial, 32 steps) ----
    if (lane == 0) {
        int e = ft;
        for (int c2 = 31; c2 >= 0; --c2) {
            earr[c2] = (uint8_t)e;
            e = Farr[c2 * 32 + e];
        }
    }
    __syncthreads();

    // ---- phase 3: re-walk chunks in parallel, emit pred (predication
    //      handles L<2: pred[t]=0 for t>=L, pred[0]=ft when L==1) ----
    if (lane < 32) {
        int tag = earr[lane];
        const int thi3 = lane * 32 + 31;
        for (int s = 0; s < 32; ++s) {
            int t = thi3 - s;
            pred[t] = (t < L) ? tag : 0;
            bool valid = (t >= 1) && (t <= L - 1);
            int tc = min(max(t, 1), max(L - 1, 1));
            int nt = bp[tc * NSTATE + tag];
            tag = valid ? nt : tag;
        }
    }
    __syncthreads();

    // ---------------- coalesced store ----------------
    int4* out4 = reinterpret_cast<int4*>(out + (size_t)blockIdx.x * T_LEN);
    const int4* p4 = reinterpret_cast<const int4*>(pred);
#pragma unroll
    for (int r = 0; r < 4; ++r)
        out4[r * 64 + lane] = p4[r * 64 + lane];
}

extern "C" void kernel_launch(void* const* d_in, const int* in_sizes, int n_in,
                              void* d_out, int out_size, void* d_ws, size_t ws_size,
                              hipStream_t stream) {
    const float* logits = (const float*)d_in[0];
    const float* trans  = (const float*)d_in[1];
    const int*   slen   = (const int*)d_in[2];
    int*         out    = (int*)d_out;
    const int B = in_sizes[2];   // 1024

    viterbi_kernel<<<dim3(B), dim3(64), 0, stream>>>(logits, trans, slen, out);
}